// Round 8
// baseline (20288.779 us; speedup 1.0000x reference)
//
#include <hip/hip_runtime.h>

#define BATCH  64
#define TT     512
#define IDIM   64
#define HDIM   512
#define NAHEAD 24
#define HB     (HDIM * BATCH)

__device__ __forceinline__ float4 ld4(const float* p) {
  return *reinterpret_cast<const float4*>(p);
}
__device__ __forceinline__ float sigm(float x) { return 1.0f / (1.0f + expf(-x)); }

// ---------------------------------------------------------------------------
// One LSTM cell tile: 2 h-cols {j0, j0+1}, all 64 batch rows. 512 threads.
// Thread = (b = tid&63, ks = tid>>6 in 0..7). 8 accumulators/thread
// (2 cols x 4 gates) over a K/8 slice; inputs loaded once per k; weight
// addresses wave-uniform. Partials [8][64][9] in LDS (stride 9 -> <=2-way
// bank aliasing, free). sm needs 8*64*9 + 8*64 floats = 20 KB.
// ---------------------------------------------------------------------------
template <int DIN0>
__device__ __forceinline__ void cell_tile2(
    int j0, const float* __restrict__ in0,             // [DIN0][B]
    const float* __restrict__ h_in,                    // [512][B]
    const float* __restrict__ w_ih,                    // [4H][DIN0]
    const float* __restrict__ w_hh,                    // [4H][512]
    const float* __restrict__ b_ih, const float* __restrict__ b_hh,
    float* __restrict__ c_state,                       // [512][B]
    float* __restrict__ h_out,                         // [512][B]
    float* __restrict__ sm)
{
  const int tid = threadIdx.x;
  const int b  = tid & 63;
  const int ks = tid >> 6;                 // 0..7, uniform per wave
  constexpr int K  = DIN0 + HDIM;
  constexpr int KS = K / 8;                // 72 (L0) / 128 (L1), %4 == 0
  const int k0 = ks * KS, k1 = k0 + KS;
  // split this thread's k-range at the DIN0 boundary (all bounds %4 == 0)
  const int a0 = (k0 < DIN0) ? k0 : DIN0;
  const int a1 = (k1 < DIN0) ? k1 : DIN0;
  const int c0 = (k0 > DIN0) ? k0 - DIN0 : 0;
  const int c1 = (k1 > DIN0) ? k1 - DIN0 : 0;

  // d = gate*2 + col: row r(d) = (d>>1)*HDIM + j0 + (d&1)
  const float* wi = w_ih + (size_t)j0 * DIN0;
  const float* wh = w_hh + (size_t)j0 * HDIM;

  float acc[8] = {0.f, 0.f, 0.f, 0.f, 0.f, 0.f, 0.f, 0.f};

#pragma unroll 2
  for (int k = a0; k < a1; k += 4) {       // input-projection slice
    float x0 = in0[(k + 0) * BATCH + b];
    float x1 = in0[(k + 1) * BATCH + b];
    float x2 = in0[(k + 2) * BATCH + b];
    float x3 = in0[(k + 3) * BATCH + b];
#pragma unroll
    for (int d = 0; d < 8; ++d) {
      float4 w = ld4(wi + (size_t)((d >> 1) * HDIM + (d & 1)) * DIN0 + k);
      acc[d] += x0 * w.x + x1 * w.y + x2 * w.z + x3 * w.w;
    }
  }
#pragma unroll 2
  for (int k = c0; k < c1; k += 4) {       // recurrent slice
    float h0 = h_in[(k + 0) * BATCH + b];
    float h1 = h_in[(k + 1) * BATCH + b];
    float h2 = h_in[(k + 2) * BATCH + b];
    float h3 = h_in[(k + 3) * BATCH + b];
#pragma unroll
    for (int d = 0; d < 8; ++d) {
      float4 w = ld4(wh + (size_t)((d >> 1) * HDIM + (d & 1)) * HDIM + k);
      acc[d] += h0 * w.x + h1 * w.y + h2 * w.z + h3 * w.w;
    }
  }

  float* gl = sm + 8 * 64 * 9;
#pragma unroll
  for (int d = 0; d < 8; ++d) sm[(d * 64 + b) * 9 + ks] = acc[d];
  __syncthreads();

  {                                         // reduce 8 partials per dot
    const int dd = tid >> 6, bb = tid & 63;
    float s = 0.f;
#pragma unroll
    for (int i = 0; i < 8; ++i) s += sm[(dd * 64 + bb) * 9 + i];
    const int r = (dd >> 1) * HDIM + j0 + (dd & 1);
    gl[dd * 64 + bb] = s + b_ih[r] + b_hh[r];
  }
  __syncthreads();

  if (tid < 128) {                          // cell update for (col, b)
    const int bb = tid & 63, cl = tid >> 6;
    const int jc = j0 + cl;
    float gi = gl[(0 + cl) * 64 + bb];      // gate order i,f,g,o
    float gf = gl[(2 + cl) * 64 + bb];
    float gg = gl[(4 + cl) * 64 + bb];
    float go = gl[(6 + cl) * 64 + bb];
    float cold = c_state[(size_t)jc * BATCH + bb];
    float cn = sigm(gf) * cold + sigm(gi) * tanhf(gg);
    float hn = sigm(go) * tanhf(cn);
    c_state[(size_t)jc * BATCH + bb] = cn;
    h_out[(size_t)jc * BATCH + bb] = hn;
  }
}

// ---------------------------------------------------------------------------
// One pipeline step, grid-parallel cells: 512 blocks x 512 threads.
// role = bid&1: 0 -> L0 cell at time t (if t<T), 1 -> L1 cell at t-1 (if t>=1).
// j0 = (bid>>1)*2. L0 writes seq0[t+1]; L1 reads seq0[t] (previous launch).
// No intra-kernel cross-block dependency; 2 blocks/CU co-resident.
// ---------------------------------------------------------------------------
__global__ __launch_bounds__(512, 4)
void lstm_step(int t,
               const float* __restrict__ xT,    // [T][I][B]
               const float* __restrict__ w_ih0, const float* __restrict__ w_hh0,
               const float* __restrict__ b_ih0, const float* __restrict__ b_hh0,
               const float* __restrict__ w_ih1, const float* __restrict__ w_hh1,
               const float* __restrict__ b_ih1, const float* __restrict__ b_hh1,
               float* __restrict__ seq0,        // [T+1][H][B]
               float* __restrict__ enc,         // [T+1][H][B]
               float* __restrict__ cst0, float* __restrict__ cst1)  // [H][B]
{
  __shared__ float sm[8 * 64 * 9 + 8 * 64];
  const int bid = blockIdx.x;
  const int j0 = (bid >> 1) * 2;
  if ((bid & 1) == 0) {
    if (t < TT)
      cell_tile2<IDIM>(j0, xT + (size_t)t * IDIM * BATCH,
                       seq0 + (size_t)t * HB,
                       w_ih0, w_hh0, b_ih0, b_hh0,
                       cst0, seq0 + (size_t)(t + 1) * HB, sm);
  } else {
    if (t >= 1)
      cell_tile2<HDIM>(j0, seq0 + (size_t)t * HB,
                       enc + (size_t)(t - 1) * HB,
                       w_ih1, w_hh1, b_ih1, b_hh1,
                       cst1, enc + (size_t)t * HB, sm);
  }
}

// ---------------------------------------------------------------------------
// Decoder gate step (xi ; h_cur) -> h_out, c in place. 256 WGs x 512.
// ---------------------------------------------------------------------------
__global__ __launch_bounds__(512, 4)
void dec_gates(const float* __restrict__ xi, const float* __restrict__ h_cur,
               const float* __restrict__ w_ih, const float* __restrict__ w_hh,
               const float* __restrict__ b_ih, const float* __restrict__ b_hh,
               float* __restrict__ cst, float* __restrict__ h_out)
{
  __shared__ float sm[8 * 64 * 9 + 8 * 64];
  cell_tile2<HDIM>(blockIdx.x * 2, xi, h_cur, w_ih, w_hh, b_ih, b_hh,
                   cst, h_out, sm);
}

// ---------------------------------------------------------------------------
// scores[t][b] = dot(enc_out[t][.][b], h_cur[.][b]); WG handles 2 t's.
// ---------------------------------------------------------------------------
__global__ __launch_bounds__(512, 2)
void attn_scores(const float* __restrict__ enc,   // [T+1][H][B]
                 const float* __restrict__ h_cur, // [H][B]
                 float* __restrict__ scores)      // [T][B]
{
  __shared__ float red[2][8][64];
  const int tid = threadIdx.x;
  const int b  = tid & 63;
  const int ks = tid >> 6;              // 0..7, k-slice of 64
  const int t0 = blockIdx.x * 2;
  const float* e0 = enc + (size_t)(t0 + 1) * HB + ks * 64 * BATCH;
  const float* e1 = e0 + HB;
  const float* hr = h_cur + ks * 64 * BATCH;
  float a0 = 0.f, a1 = 0.f;
#pragma unroll 4
  for (int k = 0; k < 64; ++k) {
    float hv = hr[k * BATCH + b];
    a0 += hv * e0[k * BATCH + b];
    a1 += hv * e1[k * BATCH + b];
  }
  red[0][ks][b] = a0;
  red[1][ks][b] = a1;
  __syncthreads();
  if (tid < 128) {
    int tl = tid >> 6;
    float s = 0.f;
#pragma unroll
    for (int i = 0; i < 8; ++i) s += red[tl][i][b];
    scores[(size_t)(t0 + tl) * BATCH + b] = s;
  }
}

// ---------------------------------------------------------------------------
// Per step s: redundant per-WG softmax over scores, ctx for 2 h-cols,
// pred_{s-1} = h_cur @ w_fc^T (rows = same 2 cols) -> out row s-1,
// xi = ctx + pred_{s-1} (dec_in). s==0: dec_in = 0, no out write.
// ---------------------------------------------------------------------------
__global__ __launch_bounds__(512, 2)
void attn_ctx(const float* __restrict__ enc,     // [T+1][H][B]
              const float* __restrict__ scores,  // [T][B]
              const float* __restrict__ h_cur,   // [H][B]
              const float* __restrict__ w_fc, const float* __restrict__ b_fc,
              float* __restrict__ xi,            // [H][B]
              float* __restrict__ out,           // [B][24][C]
              int s)
{
  __shared__ float red[8][2][64];
  __shared__ float mz[2][64];
  __shared__ float ctxv[2][64];
  const int tid = threadIdx.x;
  const int b  = tid & 63;
  const int ts = tid >> 6;              // 0..7, t-slice of 64
  const int hc0 = blockIdx.x * 2;

  // softmax stats (redundant per WG — avoids a device-wide barrier)
  float m = -1e30f;
  for (int t = ts * 64; t < ts * 64 + 64; ++t)
    m = fmaxf(m, scores[(size_t)t * BATCH + b]);
  red[ts][0][b] = m;
  __syncthreads();
  if (tid < 64) {
    float mm = red[0][0][b];
#pragma unroll
    for (int i = 1; i < 8; ++i) mm = fmaxf(mm, red[i][0][b]);
    mz[0][b] = mm;
  }
  __syncthreads();
  m = mz[0][b];
  float z = 0.f;
  for (int t = ts * 64; t < ts * 64 + 64; ++t)
    z += expf(scores[(size_t)t * BATCH + b] - m);
  red[ts][1][b] = z;
  __syncthreads();
  if (tid < 64) {
    float zz = 0.f;
#pragma unroll
    for (int i = 0; i < 8; ++i) zz += red[i][1][b];
    mz[1][b] = 1.f / zz;
  }
  __syncthreads();
  const float rZ = mz[1][b];

  // ctx for cols hc0, hc0+1 over this thread's t-slice
  float a0 = 0.f, a1 = 0.f;
  const float* eb = enc + HB + (size_t)hc0 * BATCH + b;
  for (int t = ts * 64; t < ts * 64 + 64; ++t) {
    float p = expf(scores[(size_t)t * BATCH + b] - m) * rZ;
    a0 += p * eb[(size_t)t * HB];
    a1 += p * eb[(size_t)t * HB + BATCH];
  }
  __syncthreads();
  red[ts][0][b] = a0;
  red[ts][1][b] = a1;
  __syncthreads();
  if (tid < 128) {
    int cl = tid >> 6;
    float c = 0.f;
#pragma unroll
    for (int i = 0; i < 8; ++i) c += red[i][cl][b];
    ctxv[cl][b] = c;
  }

  // pred_{s-1} for rows hc0, hc0+1 (k-sliced)
  float p0 = 0.f, p1 = 0.f;
  if (s >= 1) {
    const float* w0 = w_fc + (size_t)hc0 * HDIM + ts * 64;
    const float* w1 = w0 + HDIM;
    const float* hr = h_cur + ts * 64 * BATCH;
#pragma unroll 2
    for (int k = 0; k < 64; k += 4) {
      float4 wa = ld4(w0 + k), wb = ld4(w1 + k);
      float h0 = hr[(k + 0) * BATCH + b], h1 = hr[(k + 1) * BATCH + b];
      float h2 = hr[(k + 2) * BATCH + b], h3 = hr[(k + 3) * BATCH + b];
      p0 += wa.x * h0 + wa.y * h1 + wa.z * h2 + wa.w * h3;
      p1 += wb.x * h0 + wb.y * h1 + wb.z * h2 + wb.w * h3;
    }
  }
  __syncthreads();
  red[ts][0][b] = p0;
  red[ts][1][b] = p1;
  __syncthreads();
  if (tid < 128) {
    int cl = tid >> 6;
    int cc = hc0 + cl;
    float pred = 0.f;
    if (s >= 1) {
#pragma unroll
      for (int i = 0; i < 8; ++i) pred += red[i][cl][b];
      pred += b_fc[cc];
      out[((size_t)b * NAHEAD + (s - 1)) * HDIM + cc] = pred;
    }
    xi[(size_t)cc * BATCH + b] = ctxv[cl][b] + pred;
  }
}

// ---------------------------------------------------------------------------
// Final prediction row: out[b][srow][.] = h @ w_fc^T + b_fc
// ---------------------------------------------------------------------------
__global__ __launch_bounds__(512, 2)
void fc_out(const float* __restrict__ h, const float* __restrict__ w_fc,
            const float* __restrict__ b_fc, float* __restrict__ out, int srow)
{
  __shared__ float red[8][2][64];
  const int tid = threadIdx.x;
  const int b  = tid & 63;
  const int ks = tid >> 6;
  const int cc0 = blockIdx.x * 2;
  const float* w0 = w_fc + (size_t)cc0 * HDIM + ks * 64;
  const float* w1 = w0 + HDIM;
  const float* hr = h + ks * 64 * BATCH;
  float p0 = 0.f, p1 = 0.f;
#pragma unroll 2
  for (int k = 0; k < 64; k += 4) {
    float4 wa = ld4(w0 + k), wb = ld4(w1 + k);
    float h0 = hr[(k + 0) * BATCH + b], h1 = hr[(k + 1) * BATCH + b];
    float h2 = hr[(k + 2) * BATCH + b], h3 = hr[(k + 3) * BATCH + b];
    p0 += wa.x * h0 + wa.y * h1 + wa.z * h2 + wa.w * h3;
    p1 += wb.x * h0 + wb.y * h1 + wb.z * h2 + wb.w * h3;
  }
  red[ks][0][b] = p0;
  red[ks][1][b] = p1;
  __syncthreads();
  if (tid < 128) {
    int cl = tid >> 6;
    int cc = cc0 + cl;
    float p = 0.f;
#pragma unroll
    for (int i = 0; i < 8; ++i) p += red[i][cl][b];
    out[((size_t)b * NAHEAD + srow) * HDIM + cc] = p + b_fc[cc];
  }
}

// ---------------------------------------------------------------------------
// x [B][T][I] -> xT [T][I][B] (LDS 64x64 tile per t)
// ---------------------------------------------------------------------------
__global__ __launch_bounds__(256)
void transpose_x(const float* __restrict__ x, float* __restrict__ xT)
{
  __shared__ float tile[64][65];
  const int t = blockIdx.x;
  const int lane = threadIdx.x & 63;
  const int w    = threadIdx.x >> 6;   // 0..3
#pragma unroll
  for (int ii = 0; ii < 16; ++ii) {
    int b = w * 16 + ii;
    tile[b][lane] = x[((size_t)b * TT + t) * IDIM + lane];   // lane over i
  }
  __syncthreads();
#pragma unroll
  for (int ii = 0; ii < 16; ++ii) {
    int i = w * 16 + ii;
    xT[((size_t)t * IDIM + i) * BATCH + lane] = tile[lane][i];  // lane over b
  }
}

// ---------------------------------------------------------------------------
extern "C" void kernel_launch(void* const* d_in, const int* in_sizes, int n_in,
                              void* d_out, int out_size, void* d_ws, size_t ws_size,
                              hipStream_t stream) {
  const float* x     = (const float*)d_in[0];
  const float* w_ih0 = (const float*)d_in[1];
  const float* w_hh0 = (const float*)d_in[2];
  const float* b_ih0 = (const float*)d_in[3];
  const float* b_hh0 = (const float*)d_in[4];
  const float* w_ih1 = (const float*)d_in[5];
  const float* w_hh1 = (const float*)d_in[6];
  const float* b_ih1 = (const float*)d_in[7];
  const float* b_hh1 = (const float*)d_in[8];
  const float* w_ihd = (const float*)d_in[9];
  const float* w_hhd = (const float*)d_in[10];
  const float* b_ihd = (const float*)d_in[11];
  const float* b_hhd = (const float*)d_in[12];
  const float* w_fc  = (const float*)d_in[13];
  const float* b_fc  = (const float*)d_in[14];
  float* out = (float*)d_out;

  char* ws = (char*)d_ws;
  size_t off = 0;
  auto alloc = [&](size_t bytes) -> void* {
    void* p = ws + off;
    off += (bytes + 255) & ~(size_t)255;
    return p;
  };

  float* cst0 = (float*)alloc((size_t)HB * 4);            // zero
  float* cst1 = (float*)alloc((size_t)HB * 4);            // zero
  float* seq0 = (float*)alloc((size_t)(TT + 1) * HB * 4); // slot0 zero
  float* enc  = (float*)alloc((size_t)(TT + 1) * HB * 4); // slot0 zero
  float* xT   = (float*)alloc((size_t)TT * IDIM * BATCH * 4);
  float* scores = (float*)alloc((size_t)TT * BATCH * 4);
  float* xi     = (float*)alloc((size_t)HB * 4);
  float* hdec   = (float*)alloc((size_t)2 * HB * 4);
  (void)ws_size; (void)in_sizes; (void)n_in; (void)out_size;

  // zero the state / t=-1 slots (cst0,cst1 contiguous)
  hipMemsetAsync(cst0, 0, (size_t)HB * 4 * 2, stream);
  hipMemsetAsync(seq0, 0, (size_t)HB * 4, stream);
  hipMemsetAsync(enc,  0, (size_t)HB * 4, stream);

  transpose_x<<<TT, 256, 0, stream>>>(x, xT);

  // 513 pipelined launches: L0 step t (even blocks) + L1 step t-1 (odd).
  for (int t = 0; t <= TT; ++t) {
    lstm_step<<<512, 512, 0, stream>>>(
        t, xT, w_ih0, w_hh0, b_ih0, b_hh0,
        w_ih1, w_hh1, b_ih1, b_hh1, seq0, enc, cst0, cst1);
  }

  // decoder: h state starts at h1_{511} = enc[512]; c continues in cst1.
  const float* h_cur = enc + (size_t)TT * HB;
  for (int s = 0; s < NAHEAD; ++s) {
    attn_scores<<<256, 512, 0, stream>>>(enc, h_cur, scores);
    attn_ctx<<<256, 512, 0, stream>>>(enc, scores, h_cur, w_fc, b_fc,
                                      xi, out, s);
    float* h_nxt = hdec + (size_t)(s & 1) * HB;
    dec_gates<<<256, 512, 0, stream>>>(xi, h_cur, w_ihd, w_hhd,
                                       b_ihd, b_hhd, cst1, h_nxt);
    h_cur = h_nxt;
  }
  fc_out<<<256, 512, 0, stream>>>(h_cur, w_fc, b_fc, out, NAHEAD - 1);
}